// Round 5
// baseline (301.125 us; speedup 1.0000x reference)
//
#include <hip/hip_runtime.h>
#include <math.h>

// Problem constants
#define B_DIM 32
#define C_DIM 1024
#define MAP 784
#define NMASK 153
#define NTERM 154          // 153 masks + global-max term
#define NROW 160           // row length (154 terms + 6 zero pads; 640B rows)
#define NBIN 77            // 0=center, 1 + q*19 + (r-1)
#define DUMMY_BIN 77
#define MAX1 28            // slots for each lane's primary bin
#define MAX2 6             // slots for secondary (small) bins on lanes 51..63
#define MPW 4              // maps per wave; 2048 blocks x 4 waves x 4 = 32768
#define NBLK 2048          // grid fills machine at 8 blocks/CU when VGPR<=64
#define GRP 64             // blocks per b-group (2048 / 32 b-values)

// ---------------------------------------------------------------------------
// Compile-time gather schedule, bank-aware b32 (round-6 verified, unchanged).
// ---------------------------------------------------------------------------
struct Sched {
    unsigned short off1[MAX1][64];  // [slot][lane] byte offset, primary bin
    unsigned short off2[MAX2][64];  // [slot][lane] byte offset, secondary bin
    unsigned char  binA[64];
    unsigned char  binB[64];        // DUMMY_BIN for lanes without a 2nd bin
    bool ok;
};

constexpr Sched build_sched() {
    Sched S{};
    S.ok = true;
    short px[NBIN][40] = {};
    int   n[NBIN] = {};
    for (int i = 0; i < 28; ++i)
        for (int j = 0; j < 28; ++j) {
            int dy = i - 14, dx = j - 14, r2 = dx * dx + dy * dy;
            int p = i * 28 + j;
            if (r2 == 0) { px[0][n[0]++] = (short)p; continue; }
            if (r2 > 361) continue;            // r2>361: in NO mask
            int r = 0; while (r * r < r2) ++r; // ceil(sqrt), 1..19
            const int sx[4] = {1, -1, 1, -1}, sy[4] = {1, 1, -1, -1};
            for (int q = 0; q < 4; ++q)
                if (sx[q] * dx >= 0 && sy[q] * dy >= 0) {
                    int b = 1 + q * 19 + (r - 1);
                    if (n[b] >= 40) { S.ok = false; continue; }
                    px[b][n[b]++] = (short)p;
                }
        }
    int ord[NBIN] = {};
    for (int k = 0; k < NBIN; ++k) ord[k] = k;
    for (int a = 0; a < NBIN; ++a) {
        int best = a;
        for (int c = a + 1; c < NBIN; ++c)
            if (n[ord[c]] > n[ord[best]]) best = c;
        int t = ord[a]; ord[a] = ord[best]; ord[best] = t;
    }
    for (int l = 0; l < 64; ++l) {
        S.binA[l] = (unsigned char)ord[l];
        S.binB[l] = (l >= 51) ? (unsigned char)ord[64 + (l - 51)]
                              : (unsigned char)DUMMY_BIN;
        if (n[ord[l]] > MAX1) S.ok = false;
        if (l >= 51 && n[ord[64 + (l - 51)]] > MAX2) S.ok = false;
    }
    {   // greedy bank-aware placement, primary loop
        bool used[64][40] = {};
        for (int s = 0; s < MAX1; ++s) {
            int bankcnt[32] = {};
            for (int l = 0; l < 64; ++l) {
                int bin = S.binA[l], cnt = n[bin];
                int bestp = 0, bestload = 1 << 30; bool haveUnused = false;
                for (int t = 0; t < cnt; ++t)
                    if (!used[l][t]) {
                        int load = bankcnt[px[bin][t] % 32];
                        if (!haveUnused || load < bestload) { haveUnused = true; bestload = load; bestp = t; }
                    }
                if (!haveUnused)
                    for (int t = 0; t < cnt; ++t) {
                        int load = bankcnt[px[bin][t] % 32];
                        if (load < bestload) { bestload = load; bestp = t; }
                    }
                int p = px[bin][bestp];
                if (haveUnused) used[l][bestp] = true;
                S.off1[s][l] = (unsigned short)(p * 4);
                bankcnt[p % 32]++;
            }
        }
        for (int l = 0; l < 64; ++l)
            for (int t = 0; t < n[S.binA[l]]; ++t)
                if (!used[l][t]) S.ok = false;
    }
    {   // secondary loop
        bool used[64][40] = {};
        for (int s = 0; s < MAX2; ++s) {
            int bankcnt[32] = {};
            for (int l = 0; l < 64; ++l) {
                if (S.binB[l] == DUMMY_BIN) {
                    S.off2[s][l] = (unsigned short)((l % 32) * 4);
                    continue;
                }
                int bin = S.binB[l], cnt = n[bin];
                int bestp = 0, bestload = 1 << 30; bool haveUnused = false;
                for (int t = 0; t < cnt; ++t)
                    if (!used[l][t]) {
                        int load = bankcnt[px[bin][t] % 32];
                        if (!haveUnused || load < bestload) { haveUnused = true; bestload = load; bestp = t; }
                    }
                if (!haveUnused)
                    for (int t = 0; t < cnt; ++t) {
                        int load = bankcnt[px[bin][t] % 32];
                        if (load < bestload) { bestload = load; bestp = t; }
                    }
                int p = px[bin][bestp];
                if (haveUnused) used[l][bestp] = true;
                S.off2[s][l] = (unsigned short)(p * 4);
                bankcnt[p % 32]++;
            }
        }
        for (int l = 0; l < 64; ++l)
            if (S.binB[l] != DUMMY_BIN)
                for (int t = 0; t < n[S.binB[l]]; ++t)
                    if (!used[l][t]) S.ok = false;
    }
    return S;
}

static_assert(build_sched().ok, "schedule overflow / unplaced pixel");
__constant__ Sched d_sched = build_sched();

// sbuf per-wave layout: [0..76] bins, [77] dummy, [78..153] circles(q*19+r-1)
__device__ __forceinline__ int term_addr(int k) {
    if (k == 0) return 0;                    // center mask
    if (k >= NMASK) return DUMMY_BIN;        // 153 overridden w/ gmax; >153 -> 0
    int t = k - 1, q = (t >> 1) & 3, rm1 = t >> 3;
    return (t & 1) ? 78 + q * 19 + rm1       // circle
                   : 1 + q * 19 + rm1;       // ring
}

// ---------------- Fused kernel, per-GROUP barrier, NO SPILLS ---------------
// Round-4 post-mortem: __launch_bounds__(256,8) forced VGPR=32 -> 49 MB of
//   scratch spill stores (WRITE_SIZE 0.8->49 MB is the fingerprint) + reload
//   stalls. R4 did NOT test the group-barrier theory.
// Round-5 differential: ONLY change vs R4 is bounds (256,8)->(256,4).
//   Second arg is an allocator minimum, not a runtime cap: with actual
//   VGPR<=64 (R3 measured 60 at MPW=8; MPW=4 needs less) and LDS 18.3 KB,
//   HW still co-schedules 8 blocks/CU -> 32 waves/CU for the 2048 grid.
// Group-barrier shift-safety: groups are 64 CONSECUTIVE blocks; resident
//   capacity (>=512 blocks even at worst VGPR) >> 64, so a group straddling
//   a dispatch shift always gets its tail dispatched -> no deadlock; budget
//   failsafe remains as backstop.
__global__ __launch_bounds__(256, 4) void cac_fused(const float* __restrict__ x,
                                                    float* __restrict__ partial,
                                                    unsigned int* __restrict__ bar,
                                                    float* __restrict__ out) {
    __shared__ __align__(16) float smap[4][MAP];
    __shared__ float sbuf[4][160];           // bins + circles per wave
    __shared__ float ssqred[4][NROW];
    __shared__ float sinv[NROW];

    const int wave = threadIdx.x >> 6;
    const int lane = threadIdx.x & 63;
    const int map0 = blockIdx.x * (4 * MPW) + wave * MPW;  // 16 maps/block

    // hoisted per-lane constants
    const int linA = lane % 19;                          // segment pos (q0-q2)
    const bool inA = lane < 57, inB = lane < 19;
    const int rbA = 1 + lane;                            // lanes>=57 read q3: harmless
    const int rbB = inB ? 58 + lane : DUMMY_BIN;
    const int a0 = term_addr(lane);
    const int a1 = term_addr(lane + 64);
    const int a2 = term_addr(lane + 128);

    // prefetch map 0
    const float4 NEG4 = make_float4(-INFINITY, -INFINITY, -INFINITY, -INFINITY);
    const float4* xp4 = (const float4*)(x + (size_t)map0 * MAP);
    float4 t0 = xp4[lane], t1 = xp4[64 + lane], t2 = xp4[128 + lane];
    float4 t3 = NEG4;
    if (lane < 4) t3 = xp4[192 + lane];

    float* smw = smap[wave];
    float* sbw = sbuf[wave];
    float sq0 = 0.0f, sq1 = 0.0f, sq2 = 0.0f;
    float rr0[MPW], rr1[MPW], rr2[MPW];      // per-map term rows, in registers

    #pragma unroll
    for (int m = 0; m < MPW; ++m) {
        ((float4*)smw)[lane]       = t0;
        ((float4*)smw)[64 + lane]  = t1;
        ((float4*)smw)[128 + lane] = t2;
        if (lane < 4) ((float4*)smw)[192 + lane] = t3;
        float gmax = fmaxf(fmaxf(fmaxf(t0.x, t0.y), fmaxf(t0.z, t0.w)),
                           fmaxf(fmaxf(t1.x, t1.y), fmaxf(t1.z, t1.w)));
        gmax = fmaxf(gmax, fmaxf(fmaxf(t2.x, t2.y), fmaxf(t2.z, t2.w)));
        gmax = fmaxf(gmax, fmaxf(fmaxf(t3.x, t3.y), fmaxf(t3.z, t3.w)));

        if (m < MPW - 1) {   // software-pipeline next map's global loads
            const float4* np4 = (const float4*)(x + (size_t)(map0 + m + 1) * MAP);
            t0 = np4[lane]; t1 = np4[64 + lane]; t2 = np4[128 + lane];
            t3 = NEG4;
            if (lane < 4) t3 = np4[192 + lane];
        }
        __builtin_amdgcn_wave_barrier();     // keep LDS writes before reads

        // bank-scheduled gather (init 0 == masked-max clamp)
        const char* base = (const char*)smw;
        float m1 = 0.0f, m2v = 0.0f;
        #pragma unroll
        for (int s = 0; s < MAX1; ++s)
            m1 = fmaxf(m1, *(const float*)(base + d_sched.off1[s][lane]));
        #pragma unroll
        for (int s = 0; s < MAX2; ++s)
            m2v = fmaxf(m2v, *(const float*)(base + d_sched.off2[s][lane]));
        sbw[d_sched.binA[lane]] = m1;
        sbw[d_sched.binB[lane]] = m2v;       // dummy slot absorbs pad lanes

        #pragma unroll
        for (int off = 32; off; off >>= 1)
            gmax = fmaxf(gmax, __shfl_xor(gmax, off, 64));
        __builtin_amdgcn_wave_barrier();

        // segmented shuffle prefix-max over rings -> circles
        float cval = sbw[0];
        float rA = fmaxf(sbw[rbA], cval);    // rings: q=lane/19, r=lane%19+1
        float rB = fmaxf(sbw[rbB], cval);    // q3 rings on lanes 0..18
        #pragma unroll
        for (int s = 1; s <= 16; s <<= 1) {
            float uA = __shfl_up(rA, s, 64);
            float uB = __shfl_up(rB, s, 64);
            if (linA >= s) rA = fmaxf(rA, uA);
            if (lane >= s) rB = fmaxf(rB, uB);
        }
        if (inA) sbw[78 + lane] = rA;
        if (inB) sbw[135 + lane] = rB;
        __builtin_amdgcn_wave_barrier();

        // terms from one LDS read each; row kept in REGISTERS
        float r0 = sbw[a0];
        float r1 = sbw[a1];
        float r2 = sbw[a2];
        r2 = (lane == 25) ? gmax : (lane < 26 ? r2 : 0.0f);  // k=153 / pads

        rr0[m] = r0; rr1[m] = r1; rr2[m] = r2;
        sq0 += r0 * r0; sq1 += r1 * r1; sq2 += r2 * r2;
        __builtin_amdgcn_wave_barrier();     // next map's bin writes must not race
    }

    // block-level partial sum of squares (deterministic)
    ssqred[wave][lane]      = sq0;
    ssqred[wave][64 + lane] = sq1;
    if (lane < 32) ssqred[wave][128 + lane] = sq2;
    __syncthreads();
    if (threadIdx.x < NROW) {
        int t = threadIdx.x;
        partial[(size_t)blockIdx.x * NROW + t] =
            ssqred[0][t] + ssqred[1][t] + ssqred[2][t] + ssqred[3][t];
    }
    __syncthreads();                 // all waves' partial stores issued

    // ---- GROUP barrier: 64 blocks per b; counter at bar[group*64] ---------
    // (256B stride keeps the 32 group counters on distinct cache lines.)
    unsigned int* gbar = bar + (size_t)(blockIdx.x >> 6) * 64;
    if (threadIdx.x == 0) {
        __threadfence();             // release: flush this block's partials
        __hip_atomic_fetch_add(gbar, 1u, __ATOMIC_RELAXED, __HIP_MEMORY_SCOPE_AGENT);
        int budget = 1 << 17;        // failsafe only; group barrier can't deadlock
        while (__hip_atomic_load(gbar, __ATOMIC_RELAXED, __HIP_MEMORY_SCOPE_AGENT) < GRP
               && --budget)
            __builtin_amdgcn_s_sleep(16);   // ~1024cyc poll; <=64 pollers/line
        __threadfence();             // acquire: invalidate before peer reads
    }
    __syncthreads();

    // ---- Phase 2a: per-b norm reduce (64 partials of this group) ----------
    if (threadIdx.x < NROW) {
        int t = threadIdx.x;
        const float* p = partial + (size_t)(blockIdx.x & ~63) * NROW + t;
        float s = 0.0f;
        #pragma unroll 16
        for (int j = 0; j < GRP; ++j) s += p[(size_t)j * NROW];  // coalesced over t
        sinv[t] = (t < NTERM) ? 1.0f / (sqrtf(s) + 1e-6f) : 0.0f;
    }
    __syncthreads();

    // ---- Phase 2b: dot(row, sinv) straight from registers -----------------
    const float sl0 = sinv[lane];
    const float sl1 = sinv[64 + lane];
    const float sl2 = (lane < 32) ? sinv[128 + lane] : 0.0f;
    #pragma unroll
    for (int m = 0; m < MPW; ++m) {
        float acc = rr0[m] * sl0 + rr1[m] * sl1 + rr2[m] * sl2;  // rr2 pads are 0
        #pragma unroll
        for (int off = 32; off; off >>= 1)
            acc += __shfl_xor(acc, off, 64);
        if (lane == 0) out[map0 + m] = acc;
    }
}

extern "C" void kernel_launch(void* const* d_in, const int* in_sizes, int n_in,
                              void* d_out, int out_size, void* d_ws, size_t ws_size,
                              hipStream_t stream) {
    const float* x = (const float*)d_in[0];
    float* out = (float*)d_out;

    float* partial = (float*)d_ws;                               // 2048*160 f32 = 1.3 MB
    unsigned int* bar = (unsigned int*)((char*)d_ws +
                          (size_t)NBLK * NROW * sizeof(float));  // 32 counters, 256B apart

    hipMemsetAsync(bar, 0, 32 * 64 * sizeof(unsigned int), stream);  // zero group counters
    cac_fused<<<NBLK, 256, 0, stream>>>(x, partial, bar, out);
}

// Round 6
// 173.162 us; speedup vs baseline: 1.7390x; 1.7390x over previous
//
#include <hip/hip_runtime.h>
#include <math.h>

// Problem constants
#define B_DIM 32
#define C_DIM 1024
#define MAP 784
#define NMASK 153
#define NTERM 154          // 153 masks + global-max term
#define NROW 160           // row length (154 terms + 6 zero pads; 640B rows)
#define NBIN 77            // 0=center, 1 + q*19 + (r-1)
#define DUMMY_BIN 77
#define MAX1 28            // slots for each lane's primary bin
#define MAX2 6             // slots for secondary (small) bins on lanes 51..63
#define MPW 4              // maps per wave; 2048 blocks x 4 waves x 4 = 32768
#define NBLK 2048
#define GRP 64             // blocks per b-group (2048 / 32 b-values)

// ---------------------------------------------------------------------------
// Compile-time gather schedule, bank-aware b32 (round-6 verified, unchanged).
// ---------------------------------------------------------------------------
struct Sched {
    unsigned short off1[MAX1][64];  // [slot][lane] byte offset, primary bin
    unsigned short off2[MAX2][64];  // [slot][lane] byte offset, secondary bin
    unsigned char  binA[64];
    unsigned char  binB[64];        // DUMMY_BIN for lanes without a 2nd bin
    bool ok;
};

constexpr Sched build_sched() {
    Sched S{};
    S.ok = true;
    short px[NBIN][40] = {};
    int   n[NBIN] = {};
    for (int i = 0; i < 28; ++i)
        for (int j = 0; j < 28; ++j) {
            int dy = i - 14, dx = j - 14, r2 = dx * dx + dy * dy;
            int p = i * 28 + j;
            if (r2 == 0) { px[0][n[0]++] = (short)p; continue; }
            if (r2 > 361) continue;            // r2>361: in NO mask
            int r = 0; while (r * r < r2) ++r; // ceil(sqrt), 1..19
            const int sx[4] = {1, -1, 1, -1}, sy[4] = {1, 1, -1, -1};
            for (int q = 0; q < 4; ++q)
                if (sx[q] * dx >= 0 && sy[q] * dy >= 0) {
                    int b = 1 + q * 19 + (r - 1);
                    if (n[b] >= 40) { S.ok = false; continue; }
                    px[b][n[b]++] = (short)p;
                }
        }
    int ord[NBIN] = {};
    for (int k = 0; k < NBIN; ++k) ord[k] = k;
    for (int a = 0; a < NBIN; ++a) {
        int best = a;
        for (int c = a + 1; c < NBIN; ++c)
            if (n[ord[c]] > n[ord[best]]) best = c;
        int t = ord[a]; ord[a] = ord[best]; ord[best] = t;
    }
    for (int l = 0; l < 64; ++l) {
        S.binA[l] = (unsigned char)ord[l];
        S.binB[l] = (l >= 51) ? (unsigned char)ord[64 + (l - 51)]
                              : (unsigned char)DUMMY_BIN;
        if (n[ord[l]] > MAX1) S.ok = false;
        if (l >= 51 && n[ord[64 + (l - 51)]] > MAX2) S.ok = false;
    }
    {   // greedy bank-aware placement, primary loop
        bool used[64][40] = {};
        for (int s = 0; s < MAX1; ++s) {
            int bankcnt[32] = {};
            for (int l = 0; l < 64; ++l) {
                int bin = S.binA[l], cnt = n[bin];
                int bestp = 0, bestload = 1 << 30; bool haveUnused = false;
                for (int t = 0; t < cnt; ++t)
                    if (!used[l][t]) {
                        int load = bankcnt[px[bin][t] % 32];
                        if (!haveUnused || load < bestload) { haveUnused = true; bestload = load; bestp = t; }
                    }
                if (!haveUnused)
                    for (int t = 0; t < cnt; ++t) {
                        int load = bankcnt[px[bin][t] % 32];
                        if (load < bestload) { bestload = load; bestp = t; }
                    }
                int p = px[bin][bestp];
                if (haveUnused) used[l][bestp] = true;
                S.off1[s][l] = (unsigned short)(p * 4);
                bankcnt[p % 32]++;
            }
        }
        for (int l = 0; l < 64; ++l)
            for (int t = 0; t < n[S.binA[l]]; ++t)
                if (!used[l][t]) S.ok = false;
    }
    {   // secondary loop
        bool used[64][40] = {};
        for (int s = 0; s < MAX2; ++s) {
            int bankcnt[32] = {};
            for (int l = 0; l < 64; ++l) {
                if (S.binB[l] == DUMMY_BIN) {
                    S.off2[s][l] = (unsigned short)((l % 32) * 4);
                    continue;
                }
                int bin = S.binB[l], cnt = n[bin];
                int bestp = 0, bestload = 1 << 30; bool haveUnused = false;
                for (int t = 0; t < cnt; ++t)
                    if (!used[l][t]) {
                        int load = bankcnt[px[bin][t] % 32];
                        if (!haveUnused || load < bestload) { haveUnused = true; bestload = load; bestp = t; }
                    }
                if (!haveUnused)
                    for (int t = 0; t < cnt; ++t) {
                        int load = bankcnt[px[bin][t] % 32];
                        if (load < bestload) { bestload = load; bestp = t; }
                    }
                int p = px[bin][bestp];
                if (haveUnused) used[l][bestp] = true;
                S.off2[s][l] = (unsigned short)(p * 4);
                bankcnt[p % 32]++;
            }
        }
        for (int l = 0; l < 64; ++l)
            if (S.binB[l] != DUMMY_BIN)
                for (int t = 0; t < n[S.binB[l]]; ++t)
                    if (!used[l][t]) S.ok = false;
    }
    return S;
}

static_assert(build_sched().ok, "schedule overflow / unplaced pixel");
__constant__ Sched d_sched = build_sched();

// sbuf per-wave layout: [0..76] bins, [77] dummy, [78..153] circles(q*19+r-1)
__device__ __forceinline__ int term_addr(int k) {
    if (k == 0) return 0;                    // center mask
    if (k >= NMASK) return DUMMY_BIN;        // 153 overridden w/ gmax; >153 -> 0
    int t = k - 1, q = (t >> 1) & 3, rm1 = t >> 3;
    return (t & 1) ? 78 + q * 19 + rm1       // circle
                   : 1 + q * 19 + rm1;       // ring
}

// ---------------- Fused kernel, FENCE-FREE group barrier -------------------
// R3/R4/R5 elimination matrix: duration (~175-200us) is insensitive to
// occupancy (43<->81%), phase-1 cost (R4's 49MB spill: -7us), and counter
// contention (1 vs 32 lines). The invariant is __threadfence: on gfx950 an
// agent fence emits buffer_wbl2/buffer_inv sc1 — L2-WIDE writeback or
// invalidate. 4096 of them serialize at the 8 XCD L2s and evict x's clean
// lines from under phase-1 blocks. Fix: move `partial` through the coherence
// point with RELAXED agent-scope atomic stores/loads (global_store/load sc1:
// L2-bypass, device-coherent, NO cache-maintenance attached). Ordering:
// sc1-stores drained by __syncthreads' vmcnt(0) (completion = at coherence
// point) -> arrival RMW -> poll -> sc1-loads. Zero wbl2/inv in the kernel.
// Single-variable differential vs R5: only the partial-exchange protocol.
__global__ __launch_bounds__(256, 4) void cac_fused(const float* __restrict__ x,
                                                    float* __restrict__ partial,
                                                    unsigned int* __restrict__ bar,
                                                    float* __restrict__ out) {
    __shared__ __align__(16) float smap[4][MAP];
    __shared__ float sbuf[4][160];           // bins + circles per wave
    __shared__ float ssqred[4][NROW];
    __shared__ float sinv[NROW];

    const int wave = threadIdx.x >> 6;
    const int lane = threadIdx.x & 63;
    const int map0 = blockIdx.x * (4 * MPW) + wave * MPW;  // 16 maps/block

    // hoisted per-lane constants
    const int linA = lane % 19;                          // segment pos (q0-q2)
    const bool inA = lane < 57, inB = lane < 19;
    const int rbA = 1 + lane;                            // lanes>=57 read q3: harmless
    const int rbB = inB ? 58 + lane : DUMMY_BIN;
    const int a0 = term_addr(lane);
    const int a1 = term_addr(lane + 64);
    const int a2 = term_addr(lane + 128);

    // prefetch map 0
    const float4 NEG4 = make_float4(-INFINITY, -INFINITY, -INFINITY, -INFINITY);
    const float4* xp4 = (const float4*)(x + (size_t)map0 * MAP);
    float4 t0 = xp4[lane], t1 = xp4[64 + lane], t2 = xp4[128 + lane];
    float4 t3 = NEG4;
    if (lane < 4) t3 = xp4[192 + lane];

    float* smw = smap[wave];
    float* sbw = sbuf[wave];
    float sq0 = 0.0f, sq1 = 0.0f, sq2 = 0.0f;
    float rr0[MPW], rr1[MPW], rr2[MPW];      // per-map term rows, in registers

    #pragma unroll
    for (int m = 0; m < MPW; ++m) {
        ((float4*)smw)[lane]       = t0;
        ((float4*)smw)[64 + lane]  = t1;
        ((float4*)smw)[128 + lane] = t2;
        if (lane < 4) ((float4*)smw)[192 + lane] = t3;
        float gmax = fmaxf(fmaxf(fmaxf(t0.x, t0.y), fmaxf(t0.z, t0.w)),
                           fmaxf(fmaxf(t1.x, t1.y), fmaxf(t1.z, t1.w)));
        gmax = fmaxf(gmax, fmaxf(fmaxf(t2.x, t2.y), fmaxf(t2.z, t2.w)));
        gmax = fmaxf(gmax, fmaxf(fmaxf(t3.x, t3.y), fmaxf(t3.z, t3.w)));

        if (m < MPW - 1) {   // software-pipeline next map's global loads
            const float4* np4 = (const float4*)(x + (size_t)(map0 + m + 1) * MAP);
            t0 = np4[lane]; t1 = np4[64 + lane]; t2 = np4[128 + lane];
            t3 = NEG4;
            if (lane < 4) t3 = np4[192 + lane];
        }
        __builtin_amdgcn_wave_barrier();     // keep LDS writes before reads

        // bank-scheduled gather (init 0 == masked-max clamp)
        const char* base = (const char*)smw;
        float m1 = 0.0f, m2v = 0.0f;
        #pragma unroll
        for (int s = 0; s < MAX1; ++s)
            m1 = fmaxf(m1, *(const float*)(base + d_sched.off1[s][lane]));
        #pragma unroll
        for (int s = 0; s < MAX2; ++s)
            m2v = fmaxf(m2v, *(const float*)(base + d_sched.off2[s][lane]));
        sbw[d_sched.binA[lane]] = m1;
        sbw[d_sched.binB[lane]] = m2v;       // dummy slot absorbs pad lanes

        #pragma unroll
        for (int off = 32; off; off >>= 1)
            gmax = fmaxf(gmax, __shfl_xor(gmax, off, 64));
        __builtin_amdgcn_wave_barrier();

        // segmented shuffle prefix-max over rings -> circles
        float cval = sbw[0];
        float rA = fmaxf(sbw[rbA], cval);    // rings: q=lane/19, r=lane%19+1
        float rB = fmaxf(sbw[rbB], cval);    // q3 rings on lanes 0..18
        #pragma unroll
        for (int s = 1; s <= 16; s <<= 1) {
            float uA = __shfl_up(rA, s, 64);
            float uB = __shfl_up(rB, s, 64);
            if (linA >= s) rA = fmaxf(rA, uA);
            if (lane >= s) rB = fmaxf(rB, uB);
        }
        if (inA) sbw[78 + lane] = rA;
        if (inB) sbw[135 + lane] = rB;
        __builtin_amdgcn_wave_barrier();

        // terms from one LDS read each; row kept in REGISTERS
        float r0 = sbw[a0];
        float r1 = sbw[a1];
        float r2 = sbw[a2];
        r2 = (lane == 25) ? gmax : (lane < 26 ? r2 : 0.0f);  // k=153 / pads

        rr0[m] = r0; rr1[m] = r1; rr2[m] = r2;
        sq0 += r0 * r0; sq1 += r1 * r1; sq2 += r2 * r2;
        __builtin_amdgcn_wave_barrier();     // next map's bin writes must not race
    }

    // block-level partial sum of squares (deterministic)
    ssqred[wave][lane]      = sq0;
    ssqred[wave][64 + lane] = sq1;
    if (lane < 32) ssqred[wave][128 + lane] = sq2;
    __syncthreads();
    if (threadIdx.x < NROW) {
        int t = threadIdx.x;
        float v = ssqred[0][t] + ssqred[1][t] + ssqred[2][t] + ssqred[3][t];
        // device-coherent store: global_store sc1, write-through to the
        // coherence point. No wbl2 needed for visibility.
        __hip_atomic_store(&partial[(size_t)blockIdx.x * NROW + t], v,
                           __ATOMIC_RELAXED, __HIP_MEMORY_SCOPE_AGENT);
    }
    __syncthreads();   // emits s_waitcnt vmcnt(0): sc1-stores complete at L3

    // ---- GROUP barrier: fence-free; 64 blocks per b ------------------------
    unsigned int* gbar = bar + (size_t)(blockIdx.x >> 6) * 64;
    if (threadIdx.x == 0) {
        __hip_atomic_fetch_add(gbar, 1u, __ATOMIC_RELAXED, __HIP_MEMORY_SCOPE_AGENT);
        int budget = 1 << 17;        // failsafe only; group barrier can't deadlock
        while (__hip_atomic_load(gbar, __ATOMIC_RELAXED, __HIP_MEMORY_SCOPE_AGENT) < GRP
               && --budget)
            __builtin_amdgcn_s_sleep(16);   // ~1024cyc poll; <=64 pollers/line
    }
    __syncthreads();

    // ---- Phase 2a: per-b norm reduce (64 partials of this group) ----------
    // device-coherent loads (global_load sc1) — read the coherence point,
    // immune to stale L2 lines; no buffer_inv required.
    if (threadIdx.x < NROW) {
        int t = threadIdx.x;
        const float* p = partial + (size_t)(blockIdx.x & ~63) * NROW + t;
        float s = 0.0f;
        #pragma unroll 16
        for (int j = 0; j < GRP; ++j)
            s += __hip_atomic_load(&p[(size_t)j * NROW],
                                   __ATOMIC_RELAXED, __HIP_MEMORY_SCOPE_AGENT);
        sinv[t] = (t < NTERM) ? 1.0f / (sqrtf(s) + 1e-6f) : 0.0f;
    }
    __syncthreads();

    // ---- Phase 2b: dot(row, sinv) straight from registers -----------------
    const float sl0 = sinv[lane];
    const float sl1 = sinv[64 + lane];
    const float sl2 = (lane < 32) ? sinv[128 + lane] : 0.0f;
    #pragma unroll
    for (int m = 0; m < MPW; ++m) {
        float acc = rr0[m] * sl0 + rr1[m] * sl1 + rr2[m] * sl2;  // rr2 pads are 0
        #pragma unroll
        for (int off = 32; off; off >>= 1)
            acc += __shfl_xor(acc, off, 64);
        if (lane == 0) out[map0 + m] = acc;
    }
}

extern "C" void kernel_launch(void* const* d_in, const int* in_sizes, int n_in,
                              void* d_out, int out_size, void* d_ws, size_t ws_size,
                              hipStream_t stream) {
    const float* x = (const float*)d_in[0];
    float* out = (float*)d_out;

    float* partial = (float*)d_ws;                               // 2048*160 f32 = 1.3 MB
    unsigned int* bar = (unsigned int*)((char*)d_ws +
                          (size_t)NBLK * NROW * sizeof(float));  // 32 counters, 256B apart

    hipMemsetAsync(bar, 0, 32 * 64 * sizeof(unsigned int), stream);  // zero group counters
    cac_fused<<<NBLK, 256, 0, stream>>>(x, partial, bar, out);
}

// Round 7
// 159.313 us; speedup vs baseline: 1.8902x; 1.0869x over previous
//
#include <hip/hip_runtime.h>
#include <math.h>

// Problem constants
#define B_DIM 32
#define C_DIM 1024
#define MAP 784
#define NMASK 153
#define NTERM 154          // 153 masks + global-max term
#define NROW 160           // row length (154 terms + 6 zero pads; 640B rows)
#define NBIN 77            // 0=center, 1 + q*19 + (r-1)
#define DUMMY_BIN 77
#define MAX1 28            // slots for each lane's primary bin
#define MAX2 6             // slots for secondary (small) bins on lanes 51..63
#define MPW 8              // maps per wave; 1024 blocks x 4 waves x 8 = 32768
#define NBLK 1024          // R6 post-mortem: effective residency ~3 blocks/CU
                           // (768 blocks) -> 2048-grid ran in ~2.7 shifts (66us
                           // = 2.7 x 25us). 1024 blocks ~= one shift.
#define GRP 32             // blocks per b-group (1024 / 32 b-values)

// ---------------------------------------------------------------------------
// Compile-time gather schedule, bank-aware b32 (round-6 verified, unchanged).
// ---------------------------------------------------------------------------
struct Sched {
    unsigned short off1[MAX1][64];  // [slot][lane] byte offset, primary bin
    unsigned short off2[MAX2][64];  // [slot][lane] byte offset, secondary bin
    unsigned char  binA[64];
    unsigned char  binB[64];        // DUMMY_BIN for lanes without a 2nd bin
    bool ok;
};

constexpr Sched build_sched() {
    Sched S{};
    S.ok = true;
    short px[NBIN][40] = {};
    int   n[NBIN] = {};
    for (int i = 0; i < 28; ++i)
        for (int j = 0; j < 28; ++j) {
            int dy = i - 14, dx = j - 14, r2 = dx * dx + dy * dy;
            int p = i * 28 + j;
            if (r2 == 0) { px[0][n[0]++] = (short)p; continue; }
            if (r2 > 361) continue;            // r2>361: in NO mask
            int r = 0; while (r * r < r2) ++r; // ceil(sqrt), 1..19
            const int sx[4] = {1, -1, 1, -1}, sy[4] = {1, 1, -1, -1};
            for (int q = 0; q < 4; ++q)
                if (sx[q] * dx >= 0 && sy[q] * dy >= 0) {
                    int b = 1 + q * 19 + (r - 1);
                    if (n[b] >= 40) { S.ok = false; continue; }
                    px[b][n[b]++] = (short)p;
                }
        }
    int ord[NBIN] = {};
    for (int k = 0; k < NBIN; ++k) ord[k] = k;
    for (int a = 0; a < NBIN; ++a) {
        int best = a;
        for (int c = a + 1; c < NBIN; ++c)
            if (n[ord[c]] > n[ord[best]]) best = c;
        int t = ord[a]; ord[a] = ord[best]; ord[best] = t;
    }
    for (int l = 0; l < 64; ++l) {
        S.binA[l] = (unsigned char)ord[l];
        S.binB[l] = (l >= 51) ? (unsigned char)ord[64 + (l - 51)]
                              : (unsigned char)DUMMY_BIN;
        if (n[ord[l]] > MAX1) S.ok = false;
        if (l >= 51 && n[ord[64 + (l - 51)]] > MAX2) S.ok = false;
    }
    {   // greedy bank-aware placement, primary loop
        bool used[64][40] = {};
        for (int s = 0; s < MAX1; ++s) {
            int bankcnt[32] = {};
            for (int l = 0; l < 64; ++l) {
                int bin = S.binA[l], cnt = n[bin];
                int bestp = 0, bestload = 1 << 30; bool haveUnused = false;
                for (int t = 0; t < cnt; ++t)
                    if (!used[l][t]) {
                        int load = bankcnt[px[bin][t] % 32];
                        if (!haveUnused || load < bestload) { haveUnused = true; bestload = load; bestp = t; }
                    }
                if (!haveUnused)
                    for (int t = 0; t < cnt; ++t) {
                        int load = bankcnt[px[bin][t] % 32];
                        if (load < bestload) { bestload = load; bestp = t; }
                    }
                int p = px[bin][bestp];
                if (haveUnused) used[l][bestp] = true;
                S.off1[s][l] = (unsigned short)(p * 4);
                bankcnt[p % 32]++;
            }
        }
        for (int l = 0; l < 64; ++l)
            for (int t = 0; t < n[S.binA[l]]; ++t)
                if (!used[l][t]) S.ok = false;
    }
    {   // secondary loop
        bool used[64][40] = {};
        for (int s = 0; s < MAX2; ++s) {
            int bankcnt[32] = {};
            for (int l = 0; l < 64; ++l) {
                if (S.binB[l] == DUMMY_BIN) {
                    S.off2[s][l] = (unsigned short)((l % 32) * 4);
                    continue;
                }
                int bin = S.binB[l], cnt = n[bin];
                int bestp = 0, bestload = 1 << 30; bool haveUnused = false;
                for (int t = 0; t < cnt; ++t)
                    if (!used[l][t]) {
                        int load = bankcnt[px[bin][t] % 32];
                        if (!haveUnused || load < bestload) { haveUnused = true; bestload = load; bestp = t; }
                    }
                if (!haveUnused)
                    for (int t = 0; t < cnt; ++t) {
                        int load = bankcnt[px[bin][t] % 32];
                        if (load < bestload) { bestload = load; bestp = t; }
                    }
                int p = px[bin][bestp];
                if (haveUnused) used[l][bestp] = true;
                S.off2[s][l] = (unsigned short)(p * 4);
                bankcnt[p % 32]++;
            }
        }
        for (int l = 0; l < 64; ++l)
            if (S.binB[l] != DUMMY_BIN)
                for (int t = 0; t < n[S.binB[l]]; ++t)
                    if (!used[l][t]) S.ok = false;
    }
    return S;
}

static_assert(build_sched().ok, "schedule overflow / unplaced pixel");
__constant__ Sched d_sched = build_sched();

// sbuf per-wave layout: [0..76] bins, [77] dummy, [78..153] circles(q*19+r-1)
__device__ __forceinline__ int term_addr(int k) {
    if (k == 0) return 0;                    // center mask
    if (k >= NMASK) return DUMMY_BIN;        // 153 overridden w/ gmax; >153 -> 0
    int t = k - 1, q = (t >> 1) & 3, rm1 = t >> 3;
    return (t & 1) ? 78 + q * 19 + rm1       // circle
                   : 1 + q * 19 + rm1;       // ring
}

// ---------------- Fused kernel, fence-free barrier, ONE-SHIFT grid ---------
// R6 confirmed the fence-free sc1 protocol (198->66us). Residual gap vs the
// ~28us phase-1 floor matches dispatch-shift serialization: occupancy 38%
// => ~3 blocks/CU resident (768 blocks), 2048-grid => 2.7 shifts x ~25us
// = 66us. This round: 1024 blocks x MPW=8 (R3's proven 60-VGPR body) ->
// grid fits in ~one resident shift; per-CU work unchanged (128 maps).
// Barrier/exchange protocol byte-identical to R6.
__global__ __launch_bounds__(256, 4) void cac_fused(const float* __restrict__ x,
                                                    float* __restrict__ partial,
                                                    unsigned int* __restrict__ bar,
                                                    float* __restrict__ out) {
    __shared__ __align__(16) float smap[4][MAP];
    __shared__ float sbuf[4][160];           // bins + circles per wave
    __shared__ float ssqred[4][NROW];
    __shared__ float sinv[NROW];

    const int wave = threadIdx.x >> 6;
    const int lane = threadIdx.x & 63;
    const int map0 = blockIdx.x * (4 * MPW) + wave * MPW;  // 32 maps/block

    // hoisted per-lane constants
    const int linA = lane % 19;                          // segment pos (q0-q2)
    const bool inA = lane < 57, inB = lane < 19;
    const int rbA = 1 + lane;                            // lanes>=57 read q3: harmless
    const int rbB = inB ? 58 + lane : DUMMY_BIN;
    const int a0 = term_addr(lane);
    const int a1 = term_addr(lane + 64);
    const int a2 = term_addr(lane + 128);

    // prefetch map 0
    const float4 NEG4 = make_float4(-INFINITY, -INFINITY, -INFINITY, -INFINITY);
    const float4* xp4 = (const float4*)(x + (size_t)map0 * MAP);
    float4 t0 = xp4[lane], t1 = xp4[64 + lane], t2 = xp4[128 + lane];
    float4 t3 = NEG4;
    if (lane < 4) t3 = xp4[192 + lane];

    float* smw = smap[wave];
    float* sbw = sbuf[wave];
    float sq0 = 0.0f, sq1 = 0.0f, sq2 = 0.0f;
    float rr0[MPW], rr1[MPW], rr2[MPW];      // per-map term rows, in registers

    #pragma unroll
    for (int m = 0; m < MPW; ++m) {
        ((float4*)smw)[lane]       = t0;
        ((float4*)smw)[64 + lane]  = t1;
        ((float4*)smw)[128 + lane] = t2;
        if (lane < 4) ((float4*)smw)[192 + lane] = t3;
        float gmax = fmaxf(fmaxf(fmaxf(t0.x, t0.y), fmaxf(t0.z, t0.w)),
                           fmaxf(fmaxf(t1.x, t1.y), fmaxf(t1.z, t1.w)));
        gmax = fmaxf(gmax, fmaxf(fmaxf(t2.x, t2.y), fmaxf(t2.z, t2.w)));
        gmax = fmaxf(gmax, fmaxf(fmaxf(t3.x, t3.y), fmaxf(t3.z, t3.w)));

        if (m < MPW - 1) {   // software-pipeline next map's global loads
            const float4* np4 = (const float4*)(x + (size_t)(map0 + m + 1) * MAP);
            t0 = np4[lane]; t1 = np4[64 + lane]; t2 = np4[128 + lane];
            t3 = NEG4;
            if (lane < 4) t3 = np4[192 + lane];
        }
        __builtin_amdgcn_wave_barrier();     // keep LDS writes before reads

        // bank-scheduled gather (init 0 == masked-max clamp)
        const char* base = (const char*)smw;
        float m1 = 0.0f, m2v = 0.0f;
        #pragma unroll
        for (int s = 0; s < MAX1; ++s)
            m1 = fmaxf(m1, *(const float*)(base + d_sched.off1[s][lane]));
        #pragma unroll
        for (int s = 0; s < MAX2; ++s)
            m2v = fmaxf(m2v, *(const float*)(base + d_sched.off2[s][lane]));
        sbw[d_sched.binA[lane]] = m1;
        sbw[d_sched.binB[lane]] = m2v;       // dummy slot absorbs pad lanes

        #pragma unroll
        for (int off = 32; off; off >>= 1)
            gmax = fmaxf(gmax, __shfl_xor(gmax, off, 64));
        __builtin_amdgcn_wave_barrier();

        // segmented shuffle prefix-max over rings -> circles
        float cval = sbw[0];
        float rA = fmaxf(sbw[rbA], cval);    // rings: q=lane/19, r=lane%19+1
        float rB = fmaxf(sbw[rbB], cval);    // q3 rings on lanes 0..18
        #pragma unroll
        for (int s = 1; s <= 16; s <<= 1) {
            float uA = __shfl_up(rA, s, 64);
            float uB = __shfl_up(rB, s, 64);
            if (linA >= s) rA = fmaxf(rA, uA);
            if (lane >= s) rB = fmaxf(rB, uB);
        }
        if (inA) sbw[78 + lane] = rA;
        if (inB) sbw[135 + lane] = rB;
        __builtin_amdgcn_wave_barrier();

        // terms from one LDS read each; row kept in REGISTERS
        float r0 = sbw[a0];
        float r1 = sbw[a1];
        float r2 = sbw[a2];
        r2 = (lane == 25) ? gmax : (lane < 26 ? r2 : 0.0f);  // k=153 / pads

        rr0[m] = r0; rr1[m] = r1; rr2[m] = r2;
        sq0 += r0 * r0; sq1 += r1 * r1; sq2 += r2 * r2;
        __builtin_amdgcn_wave_barrier();     // next map's bin writes must not race
    }

    // block-level partial sum of squares (deterministic)
    ssqred[wave][lane]      = sq0;
    ssqred[wave][64 + lane] = sq1;
    if (lane < 32) ssqred[wave][128 + lane] = sq2;
    __syncthreads();
    if (threadIdx.x < NROW) {
        int t = threadIdx.x;
        float v = ssqred[0][t] + ssqred[1][t] + ssqred[2][t] + ssqred[3][t];
        // device-coherent store (global_store sc1): write-through to the
        // coherence point; no wbl2 needed for visibility.
        __hip_atomic_store(&partial[(size_t)blockIdx.x * NROW + t], v,
                           __ATOMIC_RELAXED, __HIP_MEMORY_SCOPE_AGENT);
    }
    __syncthreads();   // emits s_waitcnt vmcnt(0): sc1-stores complete at L3

    // ---- GROUP barrier: fence-free; 32 blocks per b ------------------------
    unsigned int* gbar = bar + (size_t)(blockIdx.x >> 5) * 64;  // 256B-strided
    if (threadIdx.x == 0) {
        __hip_atomic_fetch_add(gbar, 1u, __ATOMIC_RELAXED, __HIP_MEMORY_SCOPE_AGENT);
        int budget = 1 << 17;        // failsafe only; group barrier can't deadlock
        while (__hip_atomic_load(gbar, __ATOMIC_RELAXED, __HIP_MEMORY_SCOPE_AGENT) < GRP
               && --budget)
            __builtin_amdgcn_s_sleep(16);   // ~1024cyc poll; <=32 pollers/line
    }
    __syncthreads();

    // ---- Phase 2a: per-b norm reduce (32 partials of this group) ----------
    // device-coherent loads (global_load sc1): read the coherence point,
    // immune to stale L2 lines; no buffer_inv required.
    if (threadIdx.x < NROW) {
        int t = threadIdx.x;
        const float* p = partial + (size_t)(blockIdx.x & ~31) * NROW + t;
        float s = 0.0f;
        #pragma unroll 16
        for (int j = 0; j < GRP; ++j)
            s += __hip_atomic_load(&p[(size_t)j * NROW],
                                   __ATOMIC_RELAXED, __HIP_MEMORY_SCOPE_AGENT);
        sinv[t] = (t < NTERM) ? 1.0f / (sqrtf(s) + 1e-6f) : 0.0f;
    }
    __syncthreads();

    // ---- Phase 2b: dot(row, sinv) straight from registers -----------------
    const float sl0 = sinv[lane];
    const float sl1 = sinv[64 + lane];
    const float sl2 = (lane < 32) ? sinv[128 + lane] : 0.0f;
    #pragma unroll
    for (int m = 0; m < MPW; ++m) {
        float acc = rr0[m] * sl0 + rr1[m] * sl1 + rr2[m] * sl2;  // rr2 pads are 0
        #pragma unroll
        for (int off = 32; off; off >>= 1)
            acc += __shfl_xor(acc, off, 64);
        if (lane == 0) out[map0 + m] = acc;
    }
}

extern "C" void kernel_launch(void* const* d_in, const int* in_sizes, int n_in,
                              void* d_out, int out_size, void* d_ws, size_t ws_size,
                              hipStream_t stream) {
    const float* x = (const float*)d_in[0];
    float* out = (float*)d_out;

    float* partial = (float*)d_ws;                               // 1024*160 f32 = 640 KB
    unsigned int* bar = (unsigned int*)((char*)d_ws +
                          (size_t)NBLK * NROW * sizeof(float));  // 32 counters, 256B apart

    hipMemsetAsync(bar, 0, 32 * 64 * sizeof(unsigned int), stream);  // zero group counters
    cac_fused<<<NBLK, 256, 0, stream>>>(x, partial, bar, out);
}

// Round 8
// 157.903 us; speedup vs baseline: 1.9070x; 1.0089x over previous
//
#include <hip/hip_runtime.h>
#include <math.h>

// Problem constants
#define B_DIM 32
#define C_DIM 1024
#define MAP 784
#define NMASK 153
#define NTERM 154          // 153 masks + global-max term
#define NROW 160           // row length (154 terms + 6 zero pads; 640B rows)
#define NBIN 77            // 0=center, 1 + q*19 + (r-1)
#define DUMMY_BIN 77
#define MAX1 28            // slots for each lane's primary bin
#define MAX2 6             // slots for secondary (small) bins on lanes 51..63
#define MPW 8              // maps per wave; 1024 blocks x 4 waves x 8 = 32768
#define NBLK 1024
#define GRP 32             // blocks per b-group (1024 / 32 b-values)

// ---------------------------------------------------------------------------
// Compile-time gather schedule, bank-aware b32 (round-6 verified, unchanged).
// ---------------------------------------------------------------------------
struct Sched {
    unsigned short off1[MAX1][64];  // [slot][lane] byte offset, primary bin
    unsigned short off2[MAX2][64];  // [slot][lane] byte offset, secondary bin
    unsigned char  binA[64];
    unsigned char  binB[64];        // DUMMY_BIN for lanes without a 2nd bin
    bool ok;
};

constexpr Sched build_sched() {
    Sched S{};
    S.ok = true;
    short px[NBIN][40] = {};
    int   n[NBIN] = {};
    for (int i = 0; i < 28; ++i)
        for (int j = 0; j < 28; ++j) {
            int dy = i - 14, dx = j - 14, r2 = dx * dx + dy * dy;
            int p = i * 28 + j;
            if (r2 == 0) { px[0][n[0]++] = (short)p; continue; }
            if (r2 > 361) continue;            // r2>361: in NO mask
            int r = 0; while (r * r < r2) ++r; // ceil(sqrt), 1..19
            const int sx[4] = {1, -1, 1, -1}, sy[4] = {1, 1, -1, -1};
            for (int q = 0; q < 4; ++q)
                if (sx[q] * dx >= 0 && sy[q] * dy >= 0) {
                    int b = 1 + q * 19 + (r - 1);
                    if (n[b] >= 40) { S.ok = false; continue; }
                    px[b][n[b]++] = (short)p;
                }
        }
    int ord[NBIN] = {};
    for (int k = 0; k < NBIN; ++k) ord[k] = k;
    for (int a = 0; a < NBIN; ++a) {
        int best = a;
        for (int c = a + 1; c < NBIN; ++c)
            if (n[ord[c]] > n[ord[best]]) best = c;
        int t = ord[a]; ord[a] = ord[best]; ord[best] = t;
    }
    for (int l = 0; l < 64; ++l) {
        S.binA[l] = (unsigned char)ord[l];
        S.binB[l] = (l >= 51) ? (unsigned char)ord[64 + (l - 51)]
                              : (unsigned char)DUMMY_BIN;
        if (n[ord[l]] > MAX1) S.ok = false;
        if (l >= 51 && n[ord[64 + (l - 51)]] > MAX2) S.ok = false;
    }
    {   // greedy bank-aware placement, primary loop
        bool used[64][40] = {};
        for (int s = 0; s < MAX1; ++s) {
            int bankcnt[32] = {};
            for (int l = 0; l < 64; ++l) {
                int bin = S.binA[l], cnt = n[bin];
                int bestp = 0, bestload = 1 << 30; bool haveUnused = false;
                for (int t = 0; t < cnt; ++t)
                    if (!used[l][t]) {
                        int load = bankcnt[px[bin][t] % 32];
                        if (!haveUnused || load < bestload) { haveUnused = true; bestload = load; bestp = t; }
                    }
                if (!haveUnused)
                    for (int t = 0; t < cnt; ++t) {
                        int load = bankcnt[px[bin][t] % 32];
                        if (load < bestload) { bestload = load; bestp = t; }
                    }
                int p = px[bin][bestp];
                if (haveUnused) used[l][bestp] = true;
                S.off1[s][l] = (unsigned short)(p * 4);
                bankcnt[p % 32]++;
            }
        }
        for (int l = 0; l < 64; ++l)
            for (int t = 0; t < n[S.binA[l]]; ++t)
                if (!used[l][t]) S.ok = false;
    }
    {   // secondary loop
        bool used[64][40] = {};
        for (int s = 0; s < MAX2; ++s) {
            int bankcnt[32] = {};
            for (int l = 0; l < 64; ++l) {
                if (S.binB[l] == DUMMY_BIN) {
                    S.off2[s][l] = (unsigned short)((l % 32) * 4);
                    continue;
                }
                int bin = S.binB[l], cnt = n[bin];
                int bestp = 0, bestload = 1 << 30; bool haveUnused = false;
                for (int t = 0; t < cnt; ++t)
                    if (!used[l][t]) {
                        int load = bankcnt[px[bin][t] % 32];
                        if (!haveUnused || load < bestload) { haveUnused = true; bestload = load; bestp = t; }
                    }
                if (!haveUnused)
                    for (int t = 0; t < cnt; ++t) {
                        int load = bankcnt[px[bin][t] % 32];
                        if (load < bestload) { bestload = load; bestp = t; }
                    }
                int p = px[bin][bestp];
                if (haveUnused) used[l][bestp] = true;
                S.off2[s][l] = (unsigned short)(p * 4);
                bankcnt[p % 32]++;
            }
        }
        for (int l = 0; l < 64; ++l)
            if (S.binB[l] != DUMMY_BIN)
                for (int t = 0; t < n[S.binB[l]]; ++t)
                    if (!used[l][t]) S.ok = false;
    }
    return S;
}

static_assert(build_sched().ok, "schedule overflow / unplaced pixel");
__constant__ Sched d_sched = build_sched();

// sbuf per-wave layout: [0..76] bins, [77] dummy, [78..153] circles(q*19+r-1)
__device__ __forceinline__ int term_addr(int k) {
    if (k == 0) return 0;                    // center mask
    if (k >= NMASK) return DUMMY_BIN;        // 153 overridden w/ gmax; >153 -> 0
    int t = k - 1, q = (t >> 1) & 3, rm1 = t >> 3;
    return (t & 1) ? 78 + q * 19 + rm1       // circle
                   : 1 + q * 19 + rm1;       // ring
}

// ---------------- Fused kernel, fence-free barrier, UNCAPPED residency -----
// R7 post-mortem: occupancy has tracked the __launch_bounds__ 2nd arg across
// rounds — (256,8)->81% (R4), (256,4)->38-47% (R5/R6/R7, ~3 blocks/CU). The
// residual ~10us over the 22us floor is a dispatch tail: 768 resident blocks
// do phase1 at DS-rate (~12us), the last 256 blocks run after at 1 block/CU
// latency-starved (~10us). The waves-per-eu attribute the hint emits appears
// to CAP hardware residency, not just bound the allocator.
// This round, single variable: drop the hint -> __launch_bounds__(256) only.
// Compiler chose 52-60 VGPR freely before (no spill); LDS 18.4KB allows
// 8 blocks/CU -> whole 1024-block grid co-resident, one shift, no tail.
__global__ __launch_bounds__(256) void cac_fused(const float* __restrict__ x,
                                                 float* __restrict__ partial,
                                                 unsigned int* __restrict__ bar,
                                                 float* __restrict__ out) {
    __shared__ __align__(16) float smap[4][MAP];
    __shared__ float sbuf[4][160];           // bins + circles per wave
    __shared__ float ssqred[4][NROW];
    __shared__ float sinv[NROW];

    const int wave = threadIdx.x >> 6;
    const int lane = threadIdx.x & 63;
    const int map0 = blockIdx.x * (4 * MPW) + wave * MPW;  // 32 maps/block

    // hoisted per-lane constants
    const int linA = lane % 19;                          // segment pos (q0-q2)
    const bool inA = lane < 57, inB = lane < 19;
    const int rbA = 1 + lane;                            // lanes>=57 read q3: harmless
    const int rbB = inB ? 58 + lane : DUMMY_BIN;
    const int a0 = term_addr(lane);
    const int a1 = term_addr(lane + 64);
    const int a2 = term_addr(lane + 128);

    // prefetch map 0
    const float4 NEG4 = make_float4(-INFINITY, -INFINITY, -INFINITY, -INFINITY);
    const float4* xp4 = (const float4*)(x + (size_t)map0 * MAP);
    float4 t0 = xp4[lane], t1 = xp4[64 + lane], t2 = xp4[128 + lane];
    float4 t3 = NEG4;
    if (lane < 4) t3 = xp4[192 + lane];

    float* smw = smap[wave];
    float* sbw = sbuf[wave];
    float sq0 = 0.0f, sq1 = 0.0f, sq2 = 0.0f;
    float rr0[MPW], rr1[MPW], rr2[MPW];      // per-map term rows, in registers

    #pragma unroll
    for (int m = 0; m < MPW; ++m) {
        ((float4*)smw)[lane]       = t0;
        ((float4*)smw)[64 + lane]  = t1;
        ((float4*)smw)[128 + lane] = t2;
        if (lane < 4) ((float4*)smw)[192 + lane] = t3;
        float gmax = fmaxf(fmaxf(fmaxf(t0.x, t0.y), fmaxf(t0.z, t0.w)),
                           fmaxf(fmaxf(t1.x, t1.y), fmaxf(t1.z, t1.w)));
        gmax = fmaxf(gmax, fmaxf(fmaxf(t2.x, t2.y), fmaxf(t2.z, t2.w)));
        gmax = fmaxf(gmax, fmaxf(fmaxf(t3.x, t3.y), fmaxf(t3.z, t3.w)));

        if (m < MPW - 1) {   // software-pipeline next map's global loads
            const float4* np4 = (const float4*)(x + (size_t)(map0 + m + 1) * MAP);
            t0 = np4[lane]; t1 = np4[64 + lane]; t2 = np4[128 + lane];
            t3 = NEG4;
            if (lane < 4) t3 = np4[192 + lane];
        }
        __builtin_amdgcn_wave_barrier();     // keep LDS writes before reads

        // bank-scheduled gather (init 0 == masked-max clamp)
        const char* base = (const char*)smw;
        float m1 = 0.0f, m2v = 0.0f;
        #pragma unroll
        for (int s = 0; s < MAX1; ++s)
            m1 = fmaxf(m1, *(const float*)(base + d_sched.off1[s][lane]));
        #pragma unroll
        for (int s = 0; s < MAX2; ++s)
            m2v = fmaxf(m2v, *(const float*)(base + d_sched.off2[s][lane]));
        sbw[d_sched.binA[lane]] = m1;
        sbw[d_sched.binB[lane]] = m2v;       // dummy slot absorbs pad lanes

        #pragma unroll
        for (int off = 32; off; off >>= 1)
            gmax = fmaxf(gmax, __shfl_xor(gmax, off, 64));
        __builtin_amdgcn_wave_barrier();

        // segmented shuffle prefix-max over rings -> circles
        float cval = sbw[0];
        float rA = fmaxf(sbw[rbA], cval);    // rings: q=lane/19, r=lane%19+1
        float rB = fmaxf(sbw[rbB], cval);    // q3 rings on lanes 0..18
        #pragma unroll
        for (int s = 1; s <= 16; s <<= 1) {
            float uA = __shfl_up(rA, s, 64);
            float uB = __shfl_up(rB, s, 64);
            if (linA >= s) rA = fmaxf(rA, uA);
            if (lane >= s) rB = fmaxf(rB, uB);
        }
        if (inA) sbw[78 + lane] = rA;
        if (inB) sbw[135 + lane] = rB;
        __builtin_amdgcn_wave_barrier();

        // terms from one LDS read each; row kept in REGISTERS
        float r0 = sbw[a0];
        float r1 = sbw[a1];
        float r2 = sbw[a2];
        r2 = (lane == 25) ? gmax : (lane < 26 ? r2 : 0.0f);  // k=153 / pads

        rr0[m] = r0; rr1[m] = r1; rr2[m] = r2;
        sq0 += r0 * r0; sq1 += r1 * r1; sq2 += r2 * r2;
        __builtin_amdgcn_wave_barrier();     // next map's bin writes must not race
    }

    // block-level partial sum of squares (deterministic)
    ssqred[wave][lane]      = sq0;
    ssqred[wave][64 + lane] = sq1;
    if (lane < 32) ssqred[wave][128 + lane] = sq2;
    __syncthreads();
    if (threadIdx.x < NROW) {
        int t = threadIdx.x;
        float v = ssqred[0][t] + ssqred[1][t] + ssqred[2][t] + ssqred[3][t];
        // device-coherent store (global_store sc1): write-through to the
        // coherence point; no wbl2 needed for visibility.
        __hip_atomic_store(&partial[(size_t)blockIdx.x * NROW + t], v,
                           __ATOMIC_RELAXED, __HIP_MEMORY_SCOPE_AGENT);
    }
    __syncthreads();   // emits s_waitcnt vmcnt(0): sc1-stores complete at L3

    // ---- GROUP barrier: fence-free; 32 blocks per b ------------------------
    unsigned int* gbar = bar + (size_t)(blockIdx.x >> 5) * 64;  // 256B-strided
    if (threadIdx.x == 0) {
        __hip_atomic_fetch_add(gbar, 1u, __ATOMIC_RELAXED, __HIP_MEMORY_SCOPE_AGENT);
        int budget = 1 << 17;        // failsafe only; group barrier can't deadlock
        while (__hip_atomic_load(gbar, __ATOMIC_RELAXED, __HIP_MEMORY_SCOPE_AGENT) < GRP
               && --budget)
            __builtin_amdgcn_s_sleep(16);   // ~1024cyc poll; <=32 pollers/line
    }
    __syncthreads();

    // ---- Phase 2a: per-b norm reduce (32 partials of this group) ----------
    // device-coherent loads (global_load sc1): read the coherence point,
    // immune to stale L2 lines; no buffer_inv required.
    if (threadIdx.x < NROW) {
        int t = threadIdx.x;
        const float* p = partial + (size_t)(blockIdx.x & ~31) * NROW + t;
        float s = 0.0f;
        #pragma unroll 16
        for (int j = 0; j < GRP; ++j)
            s += __hip_atomic_load(&p[(size_t)j * NROW],
                                   __ATOMIC_RELAXED, __HIP_MEMORY_SCOPE_AGENT);
        sinv[t] = (t < NTERM) ? 1.0f / (sqrtf(s) + 1e-6f) : 0.0f;
    }
    __syncthreads();

    // ---- Phase 2b: dot(row, sinv) straight from registers -----------------
    const float sl0 = sinv[lane];
    const float sl1 = sinv[64 + lane];
    const float sl2 = (lane < 32) ? sinv[128 + lane] : 0.0f;
    #pragma unroll
    for (int m = 0; m < MPW; ++m) {
        float acc = rr0[m] * sl0 + rr1[m] * sl1 + rr2[m] * sl2;  // rr2 pads are 0
        #pragma unroll
        for (int off = 32; off; off >>= 1)
            acc += __shfl_xor(acc, off, 64);
        if (lane == 0) out[map0 + m] = acc;
    }
}

extern "C" void kernel_launch(void* const* d_in, const int* in_sizes, int n_in,
                              void* d_out, int out_size, void* d_ws, size_t ws_size,
                              hipStream_t stream) {
    const float* x = (const float*)d_in[0];
    float* out = (float*)d_out;

    float* partial = (float*)d_ws;                               // 1024*160 f32 = 640 KB
    unsigned int* bar = (unsigned int*)((char*)d_ws +
                          (size_t)NBLK * NROW * sizeof(float));  // 32 counters, 256B apart

    hipMemsetAsync(bar, 0, 32 * 64 * sizeof(unsigned int), stream);  // zero group counters
    cac_fused<<<NBLK, 256, 0, stream>>>(x, partial, bar, out);
}